// Round 1
// 241.230 us; speedup vs baseline: 1.0234x; 1.0234x over previous
//
#include <hip/hip_runtime.h>
#include <hip/hip_bf16.h>
#include <hip/hip_fp16.h>
#include <math.h>

#define NN 64
#define DD 128
#define PP 4800
#define KK 64
#define BPN 15          // blocks per sample n
#define PB  320         // positions per block
#define CP  64          // positions per chunk
#define NCH 5           // chunks per block

#define WT  136         // w_s  row stride (halfwords): mult of 8
#define XPT 136         // xpd  row stride (halfwords): mult of 8, chunk-swizzled columns
#define XDT 72          // xdp  row stride
#define SAT 72          // sa_s row stride

// ws element offsets
#define PAGG_SZ  ((size_t)NN * BPN * KK * DD)   // element count; fp16 now (15.7 MB)
#define PSSUM_SZ ((size_t)NN * BPN * KK)

typedef __attribute__((ext_vector_type(8))) short bf16x8;
typedef __attribute__((ext_vector_type(4))) float f32x4;

__device__ __forceinline__ unsigned short f2bf(float f) {
  unsigned u = __float_as_uint(f);
  u += 0x7fffu + ((u >> 16) & 1u);  // RNE
  return (unsigned short)(u >> 16);
}
__device__ __forceinline__ unsigned pk2(float a, float b) {
  union { __hip_bfloat162 h2; unsigned u; } cv;
  cv.h2 = __float22bfloat162_rn(make_float2(a, b));  // low = a, high = b
  return cv.u;
}

// ---------------------------------------------------------------------------
// Fused main: reg-prefetched staging (fp32 -> bf16, [d][p] + swizzled [p][d]),
// fp32 per-p ssq fused into staging, MFMA GEMM1 -> softmax -> MFMA GEMM2,
// 3 barriers per chunk, one partial-slab flush per block (no atomics).
// pagg partials stored as fp16 (vlad is dominated by the fp32 ssum*cent term,
// so fp16 error on agg partials contributes ~1e-5 absmax).
// ---------------------------------------------------------------------------
__global__ __launch_bounds__(256, 2) void main_kernel(const float* __restrict__ x,
                                                      const float* __restrict__ conv_w,
                                                      __half* __restrict__ pagg,
                                                      float* __restrict__ pssum) {
  __shared__ __align__(16) unsigned short w_s[KK * WT];    // 17408 B
  __shared__ __align__(16) unsigned short xpd[CP * XPT];   // 17408 B (col-swizzled)
  __shared__ __align__(16) unsigned short xdp[DD * XDT];   // 18432 B
  __shared__ __align__(16) unsigned short sa_s[KK * SAT];  //  9216 B
  __shared__ float red_s[256];  // [0,64): per-p ssq accumulator; flush: 256 partials

  const int b = blockIdx.x;
  const int n = b / BPN, sl = b % BPN;
  const int t = threadIdx.x, lane = t & 63, wv = t >> 6;
  const int lq = lane >> 4, ll = lane & 15;
  const int pb = t & 7, db = t >> 3;  // staging tile: p in [8pb,8pb+8), d in [4db,4db+4)

  // ---- stage conv_w -> bf16 LDS (once)
  {
    int k = t >> 2, h = t & 3;
    const float* wp = conv_w + k * DD + h * 32;
    unsigned short* dst = &w_s[k * WT + h * 32];
#pragma unroll
    for (int i = 0; i < 4; ++i) {
      float4 a = *(const float4*)(wp + 8 * i);
      float4 c = *(const float4*)(wp + 8 * i + 4);
      uint4 o = {pk2(a.x, a.y), pk2(a.z, a.w), pk2(c.x, c.y), pk2(c.z, c.w)};
      *(uint4*)&dst[8 * i] = o;
    }
  }
  if (t < 64) red_s[t] = 0.f;

  const float* xb = x + (size_t)n * DD * PP + (size_t)(4 * db) * PP + sl * PB + 8 * pb;

  float4 pf[8];
#pragma unroll
  for (int r = 0; r < 4; ++r) {
    pf[2 * r]     = *(const float4*)(xb + (size_t)r * PP);
    pf[2 * r + 1] = *(const float4*)(xb + (size_t)r * PP + 4);
  }

  f32x4 acc[8];
#pragma unroll
  for (int i = 0; i < 8; ++i) acc[i] = (f32x4){0.f, 0.f, 0.f, 0.f};
  float ssacc[16];
#pragma unroll
  for (int i = 0; i < 16; ++i) ssacc[i] = 0.f;

  for (int c = 0; c < NCH; ++c) {
    float4 cur[8];
#pragma unroll
    for (int i = 0; i < 8; ++i) cur[i] = pf[i];
    if (c + 1 < NCH) {  // prefetch next chunk; completes during this chunk's compute
      const float* xc = xb + (c + 1) * CP;
#pragma unroll
      for (int r = 0; r < 4; ++r) {
        pf[2 * r]     = *(const float4*)(xc + (size_t)r * PP);
        pf[2 * r + 1] = *(const float4*)(xc + (size_t)r * PP + 4);
      }
    }

    // ---- fp32 per-p partial sum-of-squares over this thread's 4 d-rows
    float sq[8];
#pragma unroll
    for (int h = 0; h < 2; ++h)
#pragma unroll
      for (int j = 0; j < 4; ++j) {
        float s = 0.f;
#pragma unroll
        for (int r = 0; r < 4; ++r) {
          float v = (&cur[2 * r + h].x)[j];
          s = fmaf(v, v, s);
        }
        sq[4 * h + j] = s;
      }
#pragma unroll
    for (int i = 0; i < 8; ++i) {  // reduce over the wave's 8 db values
      sq[i] += __shfl_xor(sq[i], 8);
      sq[i] += __shfl_xor(sq[i], 16);
      sq[i] += __shfl_xor(sq[i], 32);
    }

    __syncthreads();  // xpd/xdp/sa_s free (prev GEMM2 done), red_s[0:64) zeroed

    if (lane < 8) {  // one lane per p-block per wave adds its wave's partial
#pragma unroll
      for (int j = 0; j < 8; ++j) atomicAdd(&red_s[8 * lane + j], sq[j]);
    }

    // ---- convert + stage: xdp b128 rows, xpd transposed b64 (chunk-swizzled)
    {
      unsigned prow[4][4];
#pragma unroll
      for (int r = 0; r < 4; ++r) {
        const float4& a = cur[2 * r];
        const float4& c2 = cur[2 * r + 1];
        prow[r][0] = pk2(a.x, a.y);
        prow[r][1] = pk2(a.z, a.w);
        prow[r][2] = pk2(c2.x, c2.y);
        prow[r][3] = pk2(c2.z, c2.w);
        uint4 o = {prow[r][0], prow[r][1], prow[r][2], prow[r][3]};
        *(uint4*)&xdp[(4 * db + r) * XDT + 8 * pb] = o;
      }
      const int colh = (((db >> 1) ^ pb) << 3) + (db & 1) * 4;  // swizzled column
#pragma unroll
      for (int j2 = 0; j2 < 4; ++j2) {
        unsigned lo01 = __builtin_amdgcn_perm(prow[1][j2], prow[0][j2], 0x05040100u);
        unsigned hi01 = __builtin_amdgcn_perm(prow[1][j2], prow[0][j2], 0x07060302u);
        unsigned lo23 = __builtin_amdgcn_perm(prow[3][j2], prow[2][j2], 0x05040100u);
        unsigned hi23 = __builtin_amdgcn_perm(prow[3][j2], prow[2][j2], 0x07060302u);
        int p_e = 8 * pb + 2 * j2;
        *(uint2*)&xpd[p_e * XPT + colh]       = make_uint2(lo01, lo23);
        *(uint2*)&xpd[(p_e + 1) * XPT + colh] = make_uint2(hi01, hi23);
      }
    }
    __syncthreads();  // staging + ssq visible

    // ---- GEMM1 (logits) + softmax over K=64 (in-register)
    {
      const int prow_ = wv * 16 + ll;
      const int swz = (2 * wv + (ll >> 3)) & 7;
      f32x4 lg[4];
#pragma unroll
      for (int kt = 0; kt < 4; ++kt) lg[kt] = (f32x4){0.f, 0.f, 0.f, 0.f};
#pragma unroll
      for (int ks = 0; ks < 4; ++ks) {
        bf16x8 bfrag = *(const bf16x8*)&xpd[prow_ * XPT + ((((ks << 2) | lq) ^ swz) << 3)];
#pragma unroll
        for (int kt = 0; kt < 4; ++kt) {
          bf16x8 afrag = *(const bf16x8*)&w_s[(kt * 16 + ll) * WT + ks * 32 + lq * 8];
          lg[kt] = __builtin_amdgcn_mfma_f32_16x16x32_bf16(afrag, bfrag, lg[kt], 0, 0, 0);
        }
      }
      float iv = 1.0f / fmaxf(sqrtf(red_s[prow_]), 1e-12f);
      float vals[16];
      float m = -1e30f;
#pragma unroll
      for (int kt = 0; kt < 4; ++kt)
#pragma unroll
        for (int r = 0; r < 4; ++r) {
          float v = lg[kt][r] * iv;
          vals[kt * 4 + r] = v;
          m = fmaxf(m, v);
        }
      m = fmaxf(m, __shfl_xor(m, 16));
      m = fmaxf(m, __shfl_xor(m, 32));
      float se = 0.f;
#pragma unroll
      for (int i = 0; i < 16; ++i) {
        float e = __expf(vals[i] - m);
        vals[i] = e;
        se += e;
      }
      se += __shfl_xor(se, 16);
      se += __shfl_xor(se, 32);
      float rinv = 1.0f / se;
      float r2 = rinv * iv;  // fold invn into sa for GEMM2
#pragma unroll
      for (int kt = 0; kt < 4; ++kt)
#pragma unroll
        for (int r = 0; r < 4; ++r) {
          float e = vals[kt * 4 + r];
          ssacc[kt * 4 + r] += e * rinv;
          sa_s[(kt * 16 + lq * 4 + r) * SAT + prow_] = f2bf(e * r2);
        }
    }
    __syncthreads();  // sa_s visible
    if (c + 1 < NCH && t < 64) red_s[t] = 0.f;  // re-zero ssq for next chunk

    // ---- GEMM2: acc[k-tile = wv][dt] += SA * X^T over this chunk
#pragma unroll
    for (int ks = 0; ks < 2; ++ks) {
      bf16x8 afrag = *(const bf16x8*)&sa_s[(wv * 16 + ll) * SAT + ks * 32 + lq * 8];
#pragma unroll
      for (int dt = 0; dt < 8; ++dt) {
        bf16x8 bfrag = *(const bf16x8*)&xdp[(dt * 16 + ll) * XDT + ks * 32 + lq * 8];
        acc[dt] = __builtin_amdgcn_mfma_f32_16x16x32_bf16(afrag, bfrag, acc[dt], 0, 0, 0);
      }
    }
  }

  // ---- flush agg partial slab as fp16 (C-layout: k = 16wv+4lq+r, d = 16dt+ll)
  // Scalar 2B stores; the block covers its 16KB slab densely so L2 write-combines
  // to full lines — HBM writeback stays 15.7MB total.
  {
    __half* base = pagg + (size_t)(n * BPN + sl) * (KK * DD);
#pragma unroll
    for (int dt = 0; dt < 8; ++dt)
#pragma unroll
      for (int r = 0; r < 4; ++r)
        base[(16 * wv + 4 * lq + r) * DD + dt * 16 + ll] = __float2half(acc[dt][r]);
  }
  // ---- flush ssum (fp32)
#pragma unroll
  for (int i = 0; i < 16; ++i) {
    float s = ssacc[i];
    s += __shfl_xor(s, 1);
    s += __shfl_xor(s, 2);
    s += __shfl_xor(s, 4);
    s += __shfl_xor(s, 8);
    if (ll == 0) red_s[wv * 64 + (i >> 2) * 16 + lq * 4 + (i & 3)] = s;
  }
  __syncthreads();
  if (t < 64)
    pssum[(n * BPN + sl) * KK + t] =
        red_s[t] + red_s[64 + t] + red_s[128 + t] + red_s[192 + t];
}

// ---------------------------------------------------------------------------
// Fused epilogue (512 blocks): reduce 15 fp16 slabs, vlad = agg - ssum*cent,
// intra-normalize per k, then apply the ANALYTIC global norm: after
// intra-normalization every k-row has unit L2 norm (row norms here are O(100),
// far above eps), so ||vlad||_2 = sqrt(K) = 8 exactly -> multiply by 0.125
// and store straight to out. vtmp/gsum/ep2 eliminated.
// ---------------------------------------------------------------------------
__global__ __launch_bounds__(256) void ep_kernel(const __half* __restrict__ pagg,
                                                 const float* __restrict__ pssum,
                                                 const float* __restrict__ cent,
                                                 float* __restrict__ out) {
  const int blk = blockIdx.x;
  const int n = blk >> 3, kg = blk & 7;
  const int t = threadIdx.x;
  const int kl = t >> 5, c32 = t & 31;  // k-row in block, 32 lanes per row
  const int k = kg * 8 + kl;
  const size_t off = (size_t)k * DD + c32 * 4;

  const __half* base = pagg + (size_t)n * BPN * (KK * DD) + off;
  float4 a = {0.f, 0.f, 0.f, 0.f};
  for (int s = 0; s < BPN; ++s) {
    uint2 u = *(const uint2*)(base + (size_t)s * (KK * DD));
    __half2 h0 = *(const __half2*)&u.x;
    __half2 h1 = *(const __half2*)&u.y;
    float2 f0 = __half22float2(h0);
    float2 f1 = __half22float2(h1);
    a.x += f0.x; a.y += f0.y; a.z += f1.x; a.w += f1.y;
  }
  float sk = 0.f;
  for (int s = 0; s < BPN; ++s) sk += pssum[(n * BPN + s) * KK + k];

  float4 c4 = *(const float4*)(cent + off);
  float4 v;
  v.x = fmaf(-sk, c4.x, a.x);
  v.y = fmaf(-sk, c4.y, a.y);
  v.z = fmaf(-sk, c4.z, a.z);
  v.w = fmaf(-sk, c4.w, a.w);

  float ss = v.x * v.x + v.y * v.y + v.z * v.z + v.w * v.w;
  ss += __shfl_xor(ss, 1);
  ss += __shfl_xor(ss, 2);
  ss += __shfl_xor(ss, 4);
  ss += __shfl_xor(ss, 8);
  ss += __shfl_xor(ss, 16);  // row total (32 lanes per k-row)
  float scale = 0.125f / fmaxf(sqrtf(ss), 1e-12f);  // intra-norm * global 1/sqrt(64)
  v.x *= scale; v.y *= scale; v.z *= scale; v.w *= scale;
  *(float4*)(out + (size_t)n * (KK * DD) + off) = v;
}

extern "C" void kernel_launch(void* const* d_in, const int* in_sizes, int n_in,
                              void* d_out, int out_size, void* d_ws, size_t ws_size,
                              hipStream_t stream) {
  const float* x      = (const float*)d_in[0];
  const float* conv_w = (const float*)d_in[1];
  const float* cent   = (const float*)d_in[2];
  float* out = (float*)d_out;
  float* ws  = (float*)d_ws;

  __half* pagg = (__half*)ws;                 // PAGG_SZ halves = 15.7 MB
  float* pssum = ws + PAGG_SZ / 2;            // fp32, after the fp16 slab region

  main_kernel<<<NN * BPN, 256, 0, stream>>>(x, conv_w, pagg, pssum);
  ep_kernel<<<NN * 8, 256, 0, stream>>>(pagg, pssum, cent, out);
}

// Round 2
// 238.759 us; speedup vs baseline: 1.0340x; 1.0104x over previous
//
#include <hip/hip_runtime.h>
#include <hip/hip_bf16.h>
#include <hip/hip_fp16.h>
#include <math.h>

#define NN 64
#define DD 128
#define PP 4800
#define KK 64
#define BPN 15          // blocks per sample n
#define PB  320         // positions per block
#define CP  64          // positions per chunk
#define NCH 5           // chunks per block

#define WT  136         // w_s  row stride (halfwords)
#define SAT 72          // sa_s row stride
#define TSTR 72         // xdp tile stride in halfwords (4x16 bf16 subtile + 8 pad)

// ws element offsets
#define PAGG_SZ  ((size_t)NN * BPN * KK * DD)   // element count; fp16 (15.7 MB)
#define PSSUM_SZ ((size_t)NN * BPN * KK)

typedef __attribute__((ext_vector_type(8))) short bf16x8;
typedef __attribute__((ext_vector_type(4))) float f32x4;
typedef __attribute__((ext_vector_type(2))) unsigned int u32x2;
typedef __attribute__((address_space(3))) const unsigned short lds_cus;

__device__ __forceinline__ unsigned short f2bf(float f) {
  unsigned u = __float_as_uint(f);
  u += 0x7fffu + ((u >> 16) & 1u);  // RNE
  return (unsigned short)(u >> 16);
}
__device__ __forceinline__ unsigned pk2(float a, float b) {
  union { __hip_bfloat162 h2; unsigned u; } cv;
  cv.h2 = __float22bfloat162_rn(make_float2(a, b));  // low = a, high = b
  return cv.u;
}

// hw transpose read: lane g (g=lane&15) supplies tile_base + 8g bytes;
// lane l receives elems j=0..3 = lds_hw[tile_base_hw + 16j + (l&15)]
#define TR_READ(dst, addr, imm)                                          \
  asm volatile("ds_read_b64_tr_b16 %0, %1 offset:" #imm                  \
               : "=v"(dst) : "v"(addr))

// ---------------------------------------------------------------------------
// Fused main. x staged ONCE in a d-major 4x16-subtiled bf16 layout:
//   tile T(d,p) = (d>>2)*4 + (p>>4), elem at T*TSTR + (d&3)*16 + (p&15).
// GEMM2 B-frags = packed b128 rows of subtiles; GEMM1 B-frags via
// ds_read_b64_tr_b16 (hardware transpose) -> the [p][d] copy (xpd) is gone.
// LDS 63.5KB -> 45KB => 3 blocks/CU instead of 2 (latency-bound kernel).
// ---------------------------------------------------------------------------
__global__ __launch_bounds__(256, 3) void main_kernel(const float* __restrict__ x,
                                                      const float* __restrict__ conv_w,
                                                      __half* __restrict__ pagg,
                                                      float* __restrict__ pssum) {
  __shared__ __align__(16) unsigned short w_s[KK * WT];      // 17408 B
  __shared__ __align__(16) unsigned short xdp[128 * TSTR];   // 18432 B (tiled)
  __shared__ __align__(16) unsigned short sa_s[KK * SAT];    //  9216 B
  __shared__ float red_s[256];  // [0,64): per-p ssq accumulator; flush: 256 partials

  const int b = blockIdx.x;
  const int n = b / BPN, sl = b % BPN;
  const int t = threadIdx.x, lane = t & 63, wv = t >> 6;
  const int lq = lane >> 4, ll = lane & 15;
  const int pb = t & 7, db = t >> 3;  // staging tile: p in [8pb,8pb+8), d in [4db,4db+4)

  // ---- stage conv_w -> bf16 LDS (once)
  {
    int k = t >> 2, h = t & 3;
    const float* wp = conv_w + k * DD + h * 32;
    unsigned short* dst = &w_s[k * WT + h * 32];
#pragma unroll
    for (int i = 0; i < 4; ++i) {
      float4 a = *(const float4*)(wp + 8 * i);
      float4 c = *(const float4*)(wp + 8 * i + 4);
      uint4 o = {pk2(a.x, a.y), pk2(a.z, a.w), pk2(c.x, c.y), pk2(c.z, c.w)};
      *(uint4*)&dst[8 * i] = o;
    }
  }
  if (t < 64) red_s[t] = 0.f;

  const float* xb = x + (size_t)n * DD * PP + (size_t)(4 * db) * PP + sl * PB + 8 * pb;

  float4 pf[8];
#pragma unroll
  for (int r = 0; r < 4; ++r) {
    pf[2 * r]     = *(const float4*)(xb + (size_t)r * PP);
    pf[2 * r + 1] = *(const float4*)(xb + (size_t)r * PP + 4);
  }

  f32x4 acc[8];
#pragma unroll
  for (int i = 0; i < 8; ++i) acc[i] = (f32x4){0.f, 0.f, 0.f, 0.f};
  float ssacc[16];
#pragma unroll
  for (int i = 0; i < 16; ++i) ssacc[i] = 0.f;

  // staging write base: thread covers tile Tw = db*4 + (pb>>1), cols 8*(pb&1)..+8
  const int wbase = (db * 4 + (pb >> 1)) * TSTR + 8 * (pb & 1);
  // GEMM1 tr-read base (bytes as 32-bit LDS address): tile (8lq+wv), lane ll chunk
  const unsigned trbase =
      (unsigned)(size_t)((lds_cus*)xdp + (8 * lq + wv) * TSTR + 4 * ll);
  // GEMM2 b128 base (halfwords): T = (ll>>2)*4 + (lq>>1), within-tile (ll&3)*16+(lq&1)*8
  const int g2base = ((ll >> 2) * 4 + (lq >> 1)) * TSTR + (ll & 3) * 16 + (lq & 1) * 8;

  for (int c = 0; c < NCH; ++c) {
    float4 cur[8];
#pragma unroll
    for (int i = 0; i < 8; ++i) cur[i] = pf[i];
    if (c + 1 < NCH) {  // prefetch next chunk; completes during this chunk's compute
      const float* xc = xb + (c + 1) * CP;
#pragma unroll
      for (int r = 0; r < 4; ++r) {
        pf[2 * r]     = *(const float4*)(xc + (size_t)r * PP);
        pf[2 * r + 1] = *(const float4*)(xc + (size_t)r * PP + 4);
      }
    }

    // ---- fp32 per-p partial sum-of-squares over this thread's 4 d-rows
    float sq[8];
#pragma unroll
    for (int h = 0; h < 2; ++h)
#pragma unroll
      for (int j = 0; j < 4; ++j) {
        float s = 0.f;
#pragma unroll
        for (int r = 0; r < 4; ++r) {
          float v = (&cur[2 * r + h].x)[j];
          s = fmaf(v, v, s);
        }
        sq[4 * h + j] = s;
      }
#pragma unroll
    for (int i = 0; i < 8; ++i) {  // reduce over the wave's 8 db values
      sq[i] += __shfl_xor(sq[i], 8);
      sq[i] += __shfl_xor(sq[i], 16);
      sq[i] += __shfl_xor(sq[i], 32);
    }

    __syncthreads();  // xdp/sa_s free (prev GEMM2 done), red_s[0:64) zeroed

    if (lane < 8) {  // one lane per p-block per wave adds its wave's partial
#pragma unroll
      for (int j = 0; j < 8; ++j) atomicAdd(&red_s[8 * lane + j], sq[j]);
    }

    // ---- convert + stage into tiled xdp: 4x b128 per thread, subtile rows
    {
#pragma unroll
      for (int r = 0; r < 4; ++r) {
        const float4& a = cur[2 * r];
        const float4& c2 = cur[2 * r + 1];
        uint4 o = {pk2(a.x, a.y), pk2(a.z, a.w), pk2(c2.x, c2.y), pk2(c2.z, c2.w)};
        *(uint4*)&xdp[wbase + r * 16] = o;
      }
    }
    __syncthreads();  // staging + ssq visible

    // ---- GEMM1 (logits) + softmax over K=64 (in-register)
    {
      const int prow_ = wv * 16 + ll;
      // batch all 8 transpose reads (4 ks x 2 half-frags), then drain lgkm.
      // offsets: ks*32 tiles *144B = 4608*ks ; jj*4 tiles *144B = 576*jj
      u32x2 trv[8];
      TR_READ(trv[0], trbase, 0);
      TR_READ(trv[1], trbase, 576);
      TR_READ(trv[2], trbase, 4608);
      TR_READ(trv[3], trbase, 5184);
      TR_READ(trv[4], trbase, 9216);
      TR_READ(trv[5], trbase, 9792);
      TR_READ(trv[6], trbase, 13824);
      TR_READ(trv[7], trbase, 14400);
      asm volatile("s_waitcnt lgkmcnt(0)" ::: "memory");
      __builtin_amdgcn_sched_barrier(0);

      f32x4 lg[4];
#pragma unroll
      for (int kt = 0; kt < 4; ++kt) lg[kt] = (f32x4){0.f, 0.f, 0.f, 0.f};
#pragma unroll
      for (int ks = 0; ks < 4; ++ks) {
        union { unsigned u[4]; bf16x8 v; } bu;
        bu.u[0] = trv[2 * ks].x;
        bu.u[1] = trv[2 * ks].y;
        bu.u[2] = trv[2 * ks + 1].x;
        bu.u[3] = trv[2 * ks + 1].y;
        bf16x8 bfrag = bu.v;
#pragma unroll
        for (int kt = 0; kt < 4; ++kt) {
          bf16x8 afrag = *(const bf16x8*)&w_s[(kt * 16 + ll) * WT + ks * 32 + lq * 8];
          lg[kt] = __builtin_amdgcn_mfma_f32_16x16x32_bf16(afrag, bfrag, lg[kt], 0, 0, 0);
        }
      }
      float iv = 1.0f / fmaxf(sqrtf(red_s[prow_]), 1e-12f);
      float vals[16];
      float m = -1e30f;
#pragma unroll
      for (int kt = 0; kt < 4; ++kt)
#pragma unroll
        for (int r = 0; r < 4; ++r) {
          float v = lg[kt][r] * iv;
          vals[kt * 4 + r] = v;
          m = fmaxf(m, v);
        }
      m = fmaxf(m, __shfl_xor(m, 16));
      m = fmaxf(m, __shfl_xor(m, 32));
      float se = 0.f;
#pragma unroll
      for (int i = 0; i < 16; ++i) {
        float e = __expf(vals[i] - m);
        vals[i] = e;
        se += e;
      }
      se += __shfl_xor(se, 16);
      se += __shfl_xor(se, 32);
      float rinv = 1.0f / se;
      float r2 = rinv * iv;  // fold invn into sa for GEMM2
#pragma unroll
      for (int kt = 0; kt < 4; ++kt)
#pragma unroll
        for (int r = 0; r < 4; ++r) {
          float e = vals[kt * 4 + r];
          ssacc[kt * 4 + r] += e * rinv;
          sa_s[(kt * 16 + lq * 4 + r) * SAT + prow_] = f2bf(e * r2);
        }
    }
    __syncthreads();  // sa_s visible
    if (c + 1 < NCH && t < 64) red_s[t] = 0.f;  // re-zero ssq for next chunk

    // ---- GEMM2: acc[k-tile = wv][dt] += SA * X^T over this chunk (tiled reads)
#pragma unroll
    for (int ks = 0; ks < 2; ++ks) {
      bf16x8 afrag = *(const bf16x8*)&sa_s[(wv * 16 + ll) * SAT + ks * 32 + lq * 8];
#pragma unroll
      for (int dt = 0; dt < 8; ++dt) {
        bf16x8 bfrag = *(const bf16x8*)&xdp[g2base + dt * (16 * TSTR) + ks * (2 * TSTR)];
        acc[dt] = __builtin_amdgcn_mfma_f32_16x16x32_bf16(afrag, bfrag, acc[dt], 0, 0, 0);
      }
    }
  }

  // ---- flush agg partial slab as fp16 (C-layout: k = 16wv+4lq+r, d = 16dt+ll)
  {
    __half* base = pagg + (size_t)(n * BPN + sl) * (KK * DD);
#pragma unroll
    for (int dt = 0; dt < 8; ++dt)
#pragma unroll
      for (int r = 0; r < 4; ++r)
        base[(16 * wv + 4 * lq + r) * DD + dt * 16 + ll] = __float2half(acc[dt][r]);
  }
  // ---- flush ssum (fp32)
#pragma unroll
  for (int i = 0; i < 16; ++i) {
    float s = ssacc[i];
    s += __shfl_xor(s, 1);
    s += __shfl_xor(s, 2);
    s += __shfl_xor(s, 4);
    s += __shfl_xor(s, 8);
    if (ll == 0) red_s[wv * 64 + (i >> 2) * 16 + lq * 4 + (i & 3)] = s;
  }
  __syncthreads();
  if (t < 64)
    pssum[(n * BPN + sl) * KK + t] =
        red_s[t] + red_s[64 + t] + red_s[128 + t] + red_s[192 + t];
}

// ---------------------------------------------------------------------------
// Fused epilogue (512 blocks): reduce 15 fp16 slabs, vlad = agg - ssum*cent,
// intra-normalize per k, then the ANALYTIC global norm (||vlad||=sqrt(64)=8
// after intra-norm since every k-row is unit) -> *0.125, store to out.
// ---------------------------------------------------------------------------
__global__ __launch_bounds__(256) void ep_kernel(const __half* __restrict__ pagg,
                                                 const float* __restrict__ pssum,
                                                 const float* __restrict__ cent,
                                                 float* __restrict__ out) {
  const int blk = blockIdx.x;
  const int n = blk >> 3, kg = blk & 7;
  const int t = threadIdx.x;
  const int kl = t >> 5, c32 = t & 31;  // k-row in block, 32 lanes per row
  const int k = kg * 8 + kl;
  const size_t off = (size_t)k * DD + c32 * 4;

  const __half* base = pagg + (size_t)n * BPN * (KK * DD) + off;
  float4 a = {0.f, 0.f, 0.f, 0.f};
  for (int s = 0; s < BPN; ++s) {
    uint2 u = *(const uint2*)(base + (size_t)s * (KK * DD));
    __half2 h0 = *(const __half2*)&u.x;
    __half2 h1 = *(const __half2*)&u.y;
    float2 f0 = __half22float2(h0);
    float2 f1 = __half22float2(h1);
    a.x += f0.x; a.y += f0.y; a.z += f1.x; a.w += f1.y;
  }
  float sk = 0.f;
  for (int s = 0; s < BPN; ++s) sk += pssum[(n * BPN + s) * KK + k];

  float4 c4 = *(const float4*)(cent + off);
  float4 v;
  v.x = fmaf(-sk, c4.x, a.x);
  v.y = fmaf(-sk, c4.y, a.y);
  v.z = fmaf(-sk, c4.z, a.z);
  v.w = fmaf(-sk, c4.w, a.w);

  float ss = v.x * v.x + v.y * v.y + v.z * v.z + v.w * v.w;
  ss += __shfl_xor(ss, 1);
  ss += __shfl_xor(ss, 2);
  ss += __shfl_xor(ss, 4);
  ss += __shfl_xor(ss, 8);
  ss += __shfl_xor(ss, 16);  // row total (32 lanes per k-row)
  float scale = 0.125f / fmaxf(sqrtf(ss), 1e-12f);  // intra-norm * global 1/sqrt(64)
  v.x *= scale; v.y *= scale; v.z *= scale; v.w *= scale;
  *(float4*)(out + (size_t)n * (KK * DD) + off) = v;
}

extern "C" void kernel_launch(void* const* d_in, const int* in_sizes, int n_in,
                              void* d_out, int out_size, void* d_ws, size_t ws_size,
                              hipStream_t stream) {
  const float* x      = (const float*)d_in[0];
  const float* conv_w = (const float*)d_in[1];
  const float* cent   = (const float*)d_in[2];
  float* out = (float*)d_out;
  float* ws  = (float*)d_ws;

  __half* pagg = (__half*)ws;                 // PAGG_SZ halves = 15.7 MB
  float* pssum = ws + PAGG_SZ / 2;            // fp32, after the fp16 slab region

  main_kernel<<<NN * BPN, 256, 0, stream>>>(x, conv_w, pagg, pssum);
  ep_kernel<<<NN * 8, 256, 0, stream>>>(pagg, pssum, cent, out);
}